// Round 1
// baseline (399.085 us; speedup 1.0000x reference)
//
#include <hip/hip_runtime.h>
#include <hip/hip_bf16.h>

#define B_ 4
#define T_ 2048
#define C_ 1024
#define H_ 16
#define HD_ 64
#define M_ (B_*T_)        // 8192 rows
#define N3_ (3*C_)        // 3072
#define QKVSZ (B_*H_*T_*HD_)  // 8388608 elems per tensor (q, k, or v)

typedef unsigned short u16;
typedef __attribute__((ext_vector_type(8))) __bf16 bf16x8;
typedef __attribute__((ext_vector_type(4))) float f32x4;
typedef const __attribute__((address_space(1))) void* gptr_t;
typedef __attribute__((address_space(3))) void* sptr_t;

__device__ __forceinline__ u16 f2b(float f) {
  __hip_bfloat16 h = __float2bfloat16(f);
  return __builtin_bit_cast(u16, h);
}

// XOR swizzle for 64-row x 128-byte LDS tiles: spreads the 16B block index
// (bits 4-6) by row. Applied identically on write and read (rule: both sides).
__device__ __forceinline__ int swz(int row, int off) {
  return off ^ ((((row & 7) ^ ((row >> 3) & 7))) << 4);
}

// ---------------- fp32 -> bf16 convert (vectorized) ----------------
__global__ __launch_bounds__(256) void cvt_kernel(const float* __restrict__ src,
                                                  u16* __restrict__ dst, int n4) {
  int i = blockIdx.x * blockDim.x + threadIdx.x;
  int stride = gridDim.x * blockDim.x;
  for (; i < n4; i += stride) {
    float4 f = ((const float4*)src)[i];
    ushort4 o;
    o.x = f2b(f.x); o.y = f2b(f.y); o.z = f2b(f.z); o.w = f2b(f.w);
    ((ushort4*)dst)[i] = o;
  }
}

// ---------------- transpose + convert: src[K][N] fp32 -> dst[N][K] bf16 ----------------
__global__ __launch_bounds__(256) void tr_cvt(const float* __restrict__ src,
                                              u16* __restrict__ dst, int K, int N) {
  __shared__ u16 tile[64][72];   // +8 pad
  int k0 = blockIdx.x * 64, n0 = blockIdx.y * 64;
  #pragma unroll
  for (int t = 0; t < 16; ++t) {
    int idx = threadIdx.x + t * 256;
    int r = idx >> 6, c = idx & 63;
    tile[r][c] = f2b(src[(size_t)(k0 + r) * N + n0 + c]);
  }
  __syncthreads();
  #pragma unroll
  for (int t = 0; t < 16; ++t) {
    int idx = threadIdx.x + t * 256;
    int r = idx >> 6, c = idx & 63;       // r = local n, c = local k
    dst[(size_t)(n0 + r) * K + k0 + c] = tile[c][r];
  }
}

// ---------------- GEMM: C[M][N] = A[M][K] * Bt[N][K]^T + bias ----------------
// m97 structure: 128x128 tile, BK=32, 4 waves (2x2), global_load_lds width 16.
// EPI 0: scatter to q/k/v [B,H,T,HD] bf16.  EPI 1: fp32 out [M][N].
template <int EPI>
__global__ __launch_bounds__(256) void gemm_bt(const u16* __restrict__ A,
                                               const u16* __restrict__ Bt,
                                               const float* __restrict__ bias,
                                               int K, int N,
                                               u16* __restrict__ out_qkv,
                                               float* __restrict__ out_f) {
  __shared__ __align__(16) u16 As[128 * 32];
  __shared__ __align__(16) u16 Bs[128 * 32];
  const int tid = threadIdx.x;
  const int wave = tid >> 6, lane = tid & 63;
  const int m0 = blockIdx.x * 128, n0 = blockIdx.y * 128;
  const int wr = (wave >> 1) * 64, wc = (wave & 1) * 64;
  const int lr = lane & 15, lk = lane >> 4;

  f32x4 acc[4][4] = {};

  for (int kt = 0; kt < K; kt += 32) {
    #pragma unroll
    for (int i = 0; i < 2; ++i) {
      int ch = (wave * 2 + i) * 64 + lane;     // 16B chunk id, 0..511
      int row = ch >> 2, c4 = ch & 3;
      const u16* ga = A + (size_t)(m0 + row) * K + kt + c4 * 8;
      __builtin_amdgcn_global_load_lds((gptr_t)ga, (sptr_t)(As + (wave * 2 + i) * 512), 16, 0, 0);
      const u16* gb = Bt + (size_t)(n0 + row) * K + kt + c4 * 8;
      __builtin_amdgcn_global_load_lds((gptr_t)gb, (sptr_t)(Bs + (wave * 2 + i) * 512), 16, 0, 0);
    }
    __syncthreads();
    bf16x8 af[4], bfr[4];
    #pragma unroll
    for (int mi = 0; mi < 4; ++mi)
      af[mi] = *(const bf16x8*)(As + (wr + mi * 16 + lr) * 32 + lk * 8);
    #pragma unroll
    for (int ni = 0; ni < 4; ++ni)
      bfr[ni] = *(const bf16x8*)(Bs + (wc + ni * 16 + lr) * 32 + lk * 8);
    #pragma unroll
    for (int mi = 0; mi < 4; ++mi)
      #pragma unroll
      for (int ni = 0; ni < 4; ++ni)
        acc[mi][ni] = __builtin_amdgcn_mfma_f32_16x16x32_bf16(af[mi], bfr[ni], acc[mi][ni], 0, 0, 0);
    __syncthreads();
  }

  #pragma unroll
  for (int mi = 0; mi < 4; ++mi) {
    #pragma unroll
    for (int ni = 0; ni < 4; ++ni) {
      #pragma unroll
      for (int j = 0; j < 4; ++j) {
        int m = m0 + wr + mi * 16 + lk * 4 + j;    // C/D: row=(lane>>4)*4+reg
        int n = n0 + wc + ni * 16 + lr;            //      col=lane&15
        float val = acc[mi][ni][j] + bias[n];
        if (EPI == 0) {
          int sel = n >> 10, rem = n & 1023;
          int h = rem >> 6, d = rem & 63;
          int b = m >> 11, t = m & 2047;
          out_qkv[(size_t)sel * QKVSZ + (((size_t)(b * H_ + h) * T_ + t) * HD_ + d)] = f2b(val);
        } else {
          out_f[(size_t)m * C_ + n] = val;
        }
      }
    }
  }
}

// ---------------- causal flash attention ----------------
// grid: (T/64 q-tiles, B*H). 4 waves x 16 q-rows. K,Vt,P staged in swizzled LDS.
__global__ __launch_bounds__(256) void attn_k(const u16* __restrict__ q,
                                              const u16* __restrict__ k,
                                              const u16* __restrict__ v,
                                              u16* __restrict__ y) {
  __shared__ __align__(16) u16 Ks[64 * 64];
  __shared__ __align__(16) u16 Vt[64 * 64];
  __shared__ __align__(16) u16 Ps[64 * 64];
  const int tid = threadIdx.x;
  const int wave = tid >> 6, lane = tid & 63;
  const int qt = gridDim.x - 1 - blockIdx.x;     // heavy tiles first
  const int bh = blockIdx.y;
  const size_t hoff = (size_t)bh * T_ * HD_;
  const int lr = lane & 15, lk = lane >> 4;
  const int q0 = qt * 64;

  // Q fragments hoisted (global, 16B loads)
  const int qrow = q0 + wave * 16 + lr;
  bf16x8 qf0 = *(const bf16x8*)(q + hoff + (size_t)qrow * HD_ + lk * 8);
  bf16x8 qf1 = *(const bf16x8*)(q + hoff + (size_t)qrow * HD_ + 32 + lk * 8);

  f32x4 o[4] = {};
  float mrow[4], lrow[4];
  #pragma unroll
  for (int j = 0; j < 4; ++j) { mrow[j] = -1e30f; lrow[j] = 0.f; }

  for (int kt = 0; kt <= qt; ++kt) {
    __syncthreads();   // prior iter's LDS reads done before restage
    {
      const u16* kbase = k + hoff + (size_t)kt * 64 * HD_;
      const u16* vbase = v + hoff + (size_t)kt * 64 * HD_;
      #pragma unroll
      for (int i = 0; i < 2; ++i) {
        int ch = tid + i * 256;          // 0..511, 16B chunks
        int row = ch >> 3, c8 = ch & 7;
        uint4 kd = *(const uint4*)(kbase + row * HD_ + c8 * 8);
        *(uint4*)((char*)Ks + row * 128 + swz(row, c8 * 16)) = kd;
        uint4 vd = *(const uint4*)(vbase + row * HD_ + c8 * 8);
        const u16* vp = (const u16*)&vd;
        #pragma unroll
        for (int jj = 0; jj < 8; ++jj) {
          int d = c8 * 8 + jj;           // transpose: Vt[d][krow]
          *(u16*)((char*)Vt + d * 128 + swz(d, row * 2)) = vp[jj];
        }
      }
    }
    __syncthreads();

    // S = Q K^T  (per wave: 16 q-rows x 64 k-cols)
    f32x4 s[4];
    #pragma unroll
    for (int c = 0; c < 4; ++c) {
      int krow = c * 16 + lr;
      bf16x8 kf0 = *(const bf16x8*)((char*)Ks + krow * 128 + swz(krow, lk * 16));
      bf16x8 kf1 = *(const bf16x8*)((char*)Ks + krow * 128 + swz(krow, lk * 16 + 64));
      f32x4 z = {};
      z = __builtin_amdgcn_mfma_f32_16x16x32_bf16(qf0, kf0, z, 0, 0, 0);
      z = __builtin_amdgcn_mfma_f32_16x16x32_bf16(qf1, kf1, z, 0, 0, 0);
      s[c] = z;
    }

    const bool diag = (kt == qt);
    // online softmax (rows: (lane>>4)*4+j within wave strip; cols: lane&15)
    float mnew[4];
    #pragma unroll
    for (int j = 0; j < 4; ++j) {
      float mx = mrow[j];
      #pragma unroll
      for (int c = 0; c < 4; ++c) {
        float vv = s[c][j] * 0.125f;
        if (diag) {
          int kcol = c * 16 + lr;
          int qr = wave * 16 + lk * 4 + j;
          if (kcol > qr) vv = -1e30f;
        }
        s[c][j] = vv;
        mx = fmaxf(mx, vv);
      }
      #pragma unroll
      for (int off = 1; off < 16; off <<= 1)
        mx = fmaxf(mx, __shfl_xor(mx, off));
      mnew[j] = mx;
    }
    #pragma unroll
    for (int j = 0; j < 4; ++j) {
      float alpha = __expf(mrow[j] - mnew[j]);
      float rs = 0.f;
      #pragma unroll
      for (int c = 0; c < 4; ++c) {
        float p = __expf(s[c][j] - mnew[j]);
        s[c][j] = p;
        rs += p;
      }
      #pragma unroll
      for (int off = 1; off < 16; off <<= 1)
        rs += __shfl_xor(rs, off);
      lrow[j] = lrow[j] * alpha + rs;
      mrow[j] = mnew[j];
      #pragma unroll
      for (int dc = 0; dc < 4; ++dc) o[dc][j] *= alpha;
    }

    // P -> LDS (bf16, swizzled), own-wave region
    #pragma unroll
    for (int c = 0; c < 4; ++c)
      #pragma unroll
      for (int j = 0; j < 4; ++j) {
        int prow = wave * 16 + lk * 4 + j;
        int pcol = c * 16 + lr;
        *(u16*)((char*)Ps + prow * 128 + swz(prow, pcol * 2)) = f2b(s[c][j]);
      }
    __syncthreads();

    // O += P V   (A-frag from Ps, B-frag from Vt)
    int prow_f = wave * 16 + lr;
    #pragma unroll
    for (int ss = 0; ss < 2; ++ss) {
      bf16x8 pf = *(const bf16x8*)((char*)Ps + prow_f * 128 + swz(prow_f, lk * 16 + ss * 64));
      #pragma unroll
      for (int dc = 0; dc < 4; ++dc) {
        int vrow = dc * 16 + lr;
        bf16x8 vf = *(const bf16x8*)((char*)Vt + vrow * 128 + swz(vrow, lk * 16 + ss * 64));
        o[dc] = __builtin_amdgcn_mfma_f32_16x16x32_bf16(pf, vf, o[dc], 0, 0, 0);
      }
    }
  }

  // epilogue: y[b,t,h*64+d] = O / l   (bf16)
  const int b = bh >> 4, h = bh & 15;
  float linv[4];
  #pragma unroll
  for (int j = 0; j < 4; ++j) linv[j] = 1.0f / lrow[j];
  #pragma unroll
  for (int dc = 0; dc < 4; ++dc)
    #pragma unroll
    for (int j = 0; j < 4; ++j) {
      int t = q0 + wave * 16 + lk * 4 + j;
      int d = h * 64 + dc * 16 + lr;
      y[((size_t)(b * T_) + t) * C_ + d] = f2b(o[dc][j] * linv[j]);
    }
}

extern "C" void kernel_launch(void* const* d_in, const int* in_sizes, int n_in,
                              void* d_out, int out_size, void* d_ws, size_t ws_size,
                              hipStream_t stream) {
  const float* x      = (const float*)d_in[0];
  const float* W_attn = (const float*)d_in[1];
  const float* b_attn = (const float*)d_in[2];
  const float* W_proj = (const float*)d_in[3];
  const float* b_proj = (const float*)d_in[4];
  float* out = (float*)d_out;

  // workspace layout (u16 elems): xb[8M] Wat[3M] Wpt[1M] qkv[24M] y[8M] = 88MB
  u16* ws = (u16*)d_ws;
  u16* xb  = ws;
  u16* Wat = xb + (size_t)M_ * C_;
  u16* Wpt = Wat + (size_t)N3_ * C_;
  u16* qkv = Wpt + (size_t)C_ * C_;
  u16* y   = qkv + (size_t)3 * QKVSZ;

  cvt_kernel<<<2048, 256, 0, stream>>>(x, xb, M_ * C_ / 4);
  tr_cvt<<<dim3(C_ / 64, N3_ / 64), 256, 0, stream>>>(W_attn, Wat, C_, N3_);
  tr_cvt<<<dim3(C_ / 64, C_ / 64), 256, 0, stream>>>(W_proj, Wpt, C_, C_);
  gemm_bt<0><<<dim3(M_ / 128, N3_ / 128), 256, 0, stream>>>(xb, Wat, b_attn, C_, N3_, qkv, nullptr);
  attn_k<<<dim3(T_ / 64, B_ * H_), 256, 0, stream>>>(qkv, qkv + QKVSZ, qkv + 2 * QKVSZ, y);
  gemm_bt<1><<<dim3(M_ / 128, C_ / 128), 256, 0, stream>>>(y, Wpt, b_proj, C_, C_, nullptr, out);
}

// Round 2
// 273.616 us; speedup vs baseline: 1.4586x; 1.4586x over previous
//
#include <hip/hip_runtime.h>
#include <hip/hip_bf16.h>

#define B_ 4
#define T_ 2048
#define C_ 1024
#define H_ 16
#define HD_ 64
#define M_ (B_*T_)        // 8192 rows
#define N3_ (3*C_)        // 3072
#define QKVSZ (B_*H_*T_*HD_)  // 8388608 elems per tensor
#define QSCALE 0.1803368801f  // 0.125 * log2(e)

typedef unsigned short u16;
typedef __attribute__((ext_vector_type(8))) __bf16 bf16x8;
typedef __attribute__((ext_vector_type(4))) float f32x4;
typedef const __attribute__((address_space(1))) void* gptr_t;
typedef __attribute__((address_space(3))) void* sptr_t;

__device__ __forceinline__ u16 f2b(float f) {
  __hip_bfloat16 h = __float2bfloat16(f);
  return __builtin_bit_cast(u16, h);
}

// ---------------- fp32 -> bf16 convert (vectorized) ----------------
__global__ __launch_bounds__(256) void cvt_kernel(const float* __restrict__ src,
                                                  u16* __restrict__ dst, int n4) {
  int i = blockIdx.x * blockDim.x + threadIdx.x;
  int stride = gridDim.x * blockDim.x;
  for (; i < n4; i += stride) {
    float4 f = ((const float4*)src)[i];
    ushort4 o;
    o.x = f2b(f.x); o.y = f2b(f.y); o.z = f2b(f.z); o.w = f2b(f.w);
    ((ushort4*)dst)[i] = o;
  }
}

// ---------------- transpose + convert: src[K][N] fp32 -> dst[N][K] bf16 ----------------
__global__ __launch_bounds__(256) void tr_cvt(const float* __restrict__ src,
                                              u16* __restrict__ dst, int K, int N) {
  __shared__ u16 tile[64][72];   // +8 pad
  int k0 = blockIdx.x * 64, n0 = blockIdx.y * 64;
  #pragma unroll
  for (int t = 0; t < 16; ++t) {
    int idx = threadIdx.x + t * 256;
    int r = idx >> 6, c = idx & 63;
    tile[r][c] = f2b(src[(size_t)(k0 + r) * N + n0 + c]);
  }
  __syncthreads();
  #pragma unroll
  for (int t = 0; t < 16; ++t) {
    int idx = threadIdx.x + t * 256;
    int r = idx >> 6, c = idx & 63;       // r = local n, c = local k
    dst[(size_t)(n0 + r) * K + k0 + c] = tile[c][r];
  }
}

// ---------------- GEMM: C[M][N] = A[M][K] * Bt[N][K]^T + bias ----------------
// EPI 0: scatter to q (scaled) / k / v^T.  EPI 1: fp32 out [M][N].
template <int EPI>
__global__ __launch_bounds__(256) void gemm_bt(const u16* __restrict__ A,
                                               const u16* __restrict__ Bt,
                                               const float* __restrict__ bias,
                                               int K, int N,
                                               u16* __restrict__ out_qkv,
                                               float* __restrict__ out_f) {
  __shared__ __align__(16) u16 As[128 * 32];
  __shared__ __align__(16) u16 Bs[128 * 32];
  const int tid = threadIdx.x;
  const int wave = tid >> 6, lane = tid & 63;
  const int m0 = blockIdx.x * 128, n0 = blockIdx.y * 128;
  const int wr = (wave >> 1) * 64, wc = (wave & 1) * 64;
  const int lr = lane & 15, lk = lane >> 4;

  f32x4 acc[4][4] = {};

  for (int kt = 0; kt < K; kt += 32) {
    #pragma unroll
    for (int i = 0; i < 2; ++i) {
      int ch = (wave * 2 + i) * 64 + lane;     // 16B chunk id, 0..511
      int row = ch >> 2, c4 = ch & 3;
      const u16* ga = A + (size_t)(m0 + row) * K + kt + c4 * 8;
      __builtin_amdgcn_global_load_lds((gptr_t)ga, (sptr_t)(As + (wave * 2 + i) * 512), 16, 0, 0);
      const u16* gb = Bt + (size_t)(n0 + row) * K + kt + c4 * 8;
      __builtin_amdgcn_global_load_lds((gptr_t)gb, (sptr_t)(Bs + (wave * 2 + i) * 512), 16, 0, 0);
    }
    __syncthreads();
    bf16x8 af[4], bfr[4];
    #pragma unroll
    for (int mi = 0; mi < 4; ++mi)
      af[mi] = *(const bf16x8*)(As + (wr + mi * 16 + lr) * 32 + lk * 8);
    #pragma unroll
    for (int ni = 0; ni < 4; ++ni)
      bfr[ni] = *(const bf16x8*)(Bs + (wc + ni * 16 + lr) * 32 + lk * 8);
    #pragma unroll
    for (int mi = 0; mi < 4; ++mi)
      #pragma unroll
      for (int ni = 0; ni < 4; ++ni)
        acc[mi][ni] = __builtin_amdgcn_mfma_f32_16x16x32_bf16(af[mi], bfr[ni], acc[mi][ni], 0, 0, 0);
    __syncthreads();
  }

  #pragma unroll
  for (int mi = 0; mi < 4; ++mi) {
    #pragma unroll
    for (int ni = 0; ni < 4; ++ni) {
      #pragma unroll
      for (int j = 0; j < 4; ++j) {
        int m = m0 + wr + mi * 16 + lk * 4 + j;    // C/D: row=(lane>>4)*4+reg
        int n = n0 + wc + ni * 16 + lr;            //      col=lane&15
        float val = acc[mi][ni][j] + bias[n];
        if (EPI == 0) {
          int sel = n >> 10, rem = n & 1023;
          int h = rem >> 6, d = rem & 63;
          int b = m >> 11, t = m & 2047;
          size_t base = (size_t)sel * QKVSZ;
          if (sel == 0)
            out_qkv[base + (((size_t)(b * H_ + h) * T_ + t) * HD_ + d)] = f2b(val * QSCALE);
          else if (sel == 1)
            out_qkv[base + (((size_t)(b * H_ + h) * T_ + t) * HD_ + d)] = f2b(val);
          else  // v stored transposed: [b,h,d,t]
            out_qkv[base + (((size_t)(b * H_ + h) * HD_ + d) * T_ + t)] = f2b(val);
        } else {
          out_f[(size_t)m * C_ + n] = val;
        }
      }
    }
  }
}

// ---------------- causal flash attention (swapped-operand, 2-phase dbuf) ----------------
// grid: (T/64, B*H), 256 threads = 4 waves x 16 q-rows.
// S^T = mfma(K,Q): lane (g=lane>>4, q=lane&15) holds S^T[k=c*16+4g+r][q].
// Softmax per-lane (one q-row), 2 shfl_xor for cross-group reduce.
// P->LDS wave-local (b64 writes, granule-XOR swizzle), PV: O^T = mfma(Vt, P).
__global__ __launch_bounds__(256) void attn_k(const u16* __restrict__ q,
                                              const u16* __restrict__ k,
                                              const u16* __restrict__ vt,
                                              u16* __restrict__ y) {
  __shared__ __align__(16) u16 Ks[2][64 * 64];
  __shared__ __align__(16) u16 Vs[2][64 * 64];
  __shared__ __align__(16) u16 Ps[4][16 * 64];
  const int tid = threadIdx.x;
  const int wave = tid >> 6, lane = tid & 63;
  const int g = lane >> 4, lq = lane & 15;
  const int qt = gridDim.x - 1 - blockIdx.x;     // heavy tiles first
  const int bh = blockIdx.y;
  const size_t koff = (size_t)bh * T_ * HD_;     // q,k: [bh][t][d]
  const size_t voff = (size_t)bh * HD_ * T_;     // vt:  [bh][d][t]
  const int q0 = qt * 64;
  const int qloc = wave * 16 + lq;               // q row within 64-block

  // Q B-frags (q pre-scaled by 0.125*log2e in GEMM epilogue)
  const int qrow = q0 + qloc;
  bf16x8 qf0 = *(const bf16x8*)(q + koff + (size_t)qrow * HD_ + g * 8);
  bf16x8 qf1 = *(const bf16x8*)(q + koff + (size_t)qrow * HD_ + 32 + g * 8);

  f32x4 o[4] = {};
  float m = -1e30f, l = 0.f;

  auto stage = [&](int buf, int kt) {
    const u16* kb = k + koff + (size_t)kt * 64 * HD_;
    const u16* vb = vt + voff + (size_t)kt * 64;
    #pragma unroll
    for (int j = 0; j < 2; ++j) {
      int cb = j * 256 + wave * 64;          // wave-uniform chunk base
      int ch = cb + lane;
      int row = ch >> 3, gsw = ch & 7;
      int src = gsw ^ (row & 7);             // pre-swizzled global source granule
      __builtin_amdgcn_global_load_lds((gptr_t)(kb + row * HD_ + src * 8),
                                       (sptr_t)(&Ks[buf][cb * 8]), 16, 0, 0);
      __builtin_amdgcn_global_load_lds((gptr_t)(vb + (size_t)row * T_ + src * 8),
                                       (sptr_t)(&Vs[buf][cb * 8]), 16, 0, 0);
    }
  };

  const int ns = qt + 1;
  stage(0, 0);
  __syncthreads();

  for (int kt = 0; kt < ns; ++kt) {
    const int cur = kt & 1;
    if (kt + 1 < ns) stage(cur ^ 1, kt + 1);
    const bool diag = (kt == qt);
    const u16* Kb = &Ks[cur][0];
    const u16* Vb = &Vs[cur][0];

    // ---- S^T = K Q^T (swapped) ----
    f32x4 s[4];
    #pragma unroll
    for (int c = 0; c < 4; ++c) {
      if (diag && c > wave) {
        s[c][0] = s[c][1] = s[c][2] = s[c][3] = -1e30f;
        continue;
      }
      int kr = c * 16 + lq;
      const u16* rowp = Kb + kr * 64;
      bf16x8 kf0 = *(const bf16x8*)(rowp + ((g ^ (kr & 7)) << 3));
      bf16x8 kf1 = *(const bf16x8*)(rowp + (((4 + g) ^ (kr & 7)) << 3));
      f32x4 z = {};
      z = __builtin_amdgcn_mfma_f32_16x16x32_bf16(kf0, qf0, z, 0, 0, 0);
      z = __builtin_amdgcn_mfma_f32_16x16x32_bf16(kf1, qf1, z, 0, 0, 0);
      s[c] = z;
    }
    if (diag) {
      #pragma unroll
      for (int c = 0; c < 4; ++c)
        #pragma unroll
        for (int r = 0; r < 4; ++r)
          if (c * 16 + 4 * g + r > qloc) s[c][r] = -1e30f;
    }

    // ---- online softmax (per-lane row; 2 shfls per reduce) ----
    float tm = -1e30f;
    #pragma unroll
    for (int c = 0; c < 4; ++c)
      #pragma unroll
      for (int r = 0; r < 4; ++r)
        tm = fmaxf(tm, s[c][r]);
    tm = fmaxf(tm, __shfl_xor(tm, 16));
    tm = fmaxf(tm, __shfl_xor(tm, 32));
    if (__any(tm > m + 8.f)) {               // defer-max (T13)
      float mn = fmaxf(m, tm);
      float al = exp2f(m - mn);
      l *= al;
      #pragma unroll
      for (int dc = 0; dc < 4; ++dc) o[dc] *= al;
      m = mn;
    }
    float rs = 0.f;
    #pragma unroll
    for (int c = 0; c < 4; ++c)
      #pragma unroll
      for (int r = 0; r < 4; ++r) {
        float p = exp2f(s[c][r] - m);
        s[c][r] = p;
        rs += p;
      }
    rs += __shfl_xor(rs, 16);
    rs += __shfl_xor(rs, 32);
    l += rs;

    // ---- P -> LDS (wave-local region, granule-XOR swizzle) ----
    u16* pw = &Ps[wave][0];
    #pragma unroll
    for (int c = 0; c < 4; ++c) {
      ushort4 pk;
      pk.x = f2b(s[c][0]); pk.y = f2b(s[c][1]);
      pk.z = f2b(s[c][2]); pk.w = f2b(s[c][3]);
      int gi = (c * 2 + (g >> 1)) ^ (lq & 7);
      *(ushort4*)(pw + lq * 64 + gi * 8 + (g & 1) * 4) = pk;
    }
    bf16x8 pf0 = *(const bf16x8*)(pw + lq * 64 + ((g ^ (lq & 7)) << 3));
    bf16x8 pf1 = *(const bf16x8*)(pw + lq * 64 + (((4 + g) ^ (lq & 7)) << 3));

    // ---- O^T += Vt P  (A=Vt rows d, B=P) ----
    #pragma unroll
    for (int ss = 0; ss < 2; ++ss) {
      if (diag && ss > (wave >> 1)) continue;   // k>=32 fully masked for waves 0,1
      bf16x8 pf = ss ? pf1 : pf0;
      #pragma unroll
      for (int dc = 0; dc < 4; ++dc) {
        int dr = dc * 16 + lq;
        bf16x8 vf = *(const bf16x8*)(Vb + dr * 64 + (((ss * 4 + g) ^ (dr & 7)) << 3));
        o[dc] = __builtin_amdgcn_mfma_f32_16x16x32_bf16(vf, pf, o[dc], 0, 0, 0);
      }
    }
    __syncthreads();
  }

  // ---- epilogue: y[b,t,h*64+d] = O^T[d][q]/l ----
  const int b = bh >> 4, h = bh & 15;
  const int t = q0 + qloc;
  float li = 1.0f / l;
  #pragma unroll
  for (int dc = 0; dc < 4; ++dc) {
    ushort4 st;
    st.x = f2b(o[dc][0] * li); st.y = f2b(o[dc][1] * li);
    st.z = f2b(o[dc][2] * li); st.w = f2b(o[dc][3] * li);
    *(ushort4*)(y + ((size_t)(b * T_ + t)) * C_ + h * 64 + dc * 16 + 4 * g) = st;
  }
}

extern "C" void kernel_launch(void* const* d_in, const int* in_sizes, int n_in,
                              void* d_out, int out_size, void* d_ws, size_t ws_size,
                              hipStream_t stream) {
  const float* x      = (const float*)d_in[0];
  const float* W_attn = (const float*)d_in[1];
  const float* b_attn = (const float*)d_in[2];
  const float* W_proj = (const float*)d_in[3];
  const float* b_proj = (const float*)d_in[4];
  float* out = (float*)d_out;

  u16* ws = (u16*)d_ws;
  u16* xb  = ws;
  u16* Wat = xb + (size_t)M_ * C_;
  u16* Wpt = Wat + (size_t)N3_ * C_;
  u16* qkv = Wpt + (size_t)C_ * C_;
  u16* y   = qkv + (size_t)3 * QKVSZ;

  cvt_kernel<<<2048, 256, 0, stream>>>(x, xb, M_ * C_ / 4);
  tr_cvt<<<dim3(C_ / 64, N3_ / 64), 256, 0, stream>>>(W_attn, Wat, C_, N3_);
  tr_cvt<<<dim3(C_ / 64, C_ / 64), 256, 0, stream>>>(W_proj, Wpt, C_, C_);
  gemm_bt<0><<<dim3(M_ / 128, N3_ / 128), 256, 0, stream>>>(xb, Wat, b_attn, C_, N3_, qkv, nullptr);
  attn_k<<<dim3(T_ / 64, B_ * H_), 256, 0, stream>>>(qkv, qkv + QKVSZ, qkv + 2 * QKVSZ, y);
  gemm_bt<1><<<dim3(M_ / 128, C_ / 128), 256, 0, stream>>>(y, Wpt, b_proj, C_, C_, nullptr, out);
}

// Round 3
// 228.718 us; speedup vs baseline: 1.7449x; 1.1963x over previous
//
#include <hip/hip_runtime.h>
#include <hip/hip_bf16.h>

#define B_ 4
#define T_ 2048
#define C_ 1024
#define H_ 16
#define HD_ 64
#define M_ (B_*T_)        // 8192 rows
#define N3_ (3*C_)        // 3072
#define QKVSZ (B_*H_*T_*HD_)  // 8388608 elems per tensor
#define QSCALE 0.1803368801f  // 0.125 * log2(e)

typedef unsigned short u16;
typedef unsigned int u32;
typedef __attribute__((ext_vector_type(8))) __bf16 bf16x8;
typedef __attribute__((ext_vector_type(4))) float f32x4;
typedef __attribute__((ext_vector_type(16))) float f32x16;
typedef __attribute__((ext_vector_type(2))) int i32x2;
typedef __attribute__((ext_vector_type(4))) u32 u32x4;
typedef const __attribute__((address_space(1))) void* gptr_t;
typedef __attribute__((address_space(3))) void* sptr_t;

__device__ __forceinline__ u16 f2b(float f) {
  __hip_bfloat16 h = __float2bfloat16(f);
  return __builtin_bit_cast(u16, h);
}

// v_cvt_pk_bf16_f32: lo -> bits[15:0], hi -> bits[31:16]
__device__ __forceinline__ u32 cvtpk(float lo, float hi) {
  u32 r;
  asm volatile("v_cvt_pk_bf16_f32 %0, %1, %2" : "=v"(r) : "v"(lo), "v"(hi));
  return r;
}

// ---------------- fp32 -> bf16 convert (vectorized) ----------------
__global__ __launch_bounds__(256) void cvt_kernel(const float* __restrict__ src,
                                                  u16* __restrict__ dst, int n4) {
  int i = blockIdx.x * blockDim.x + threadIdx.x;
  int stride = gridDim.x * blockDim.x;
  for (; i < n4; i += stride) {
    float4 f = ((const float4*)src)[i];
    ushort4 o;
    o.x = f2b(f.x); o.y = f2b(f.y); o.z = f2b(f.z); o.w = f2b(f.w);
    ((ushort4*)dst)[i] = o;
  }
}

// ---------------- transpose + convert: src[K][N] fp32 -> dst[N][K] bf16 ----------------
__global__ __launch_bounds__(256) void tr_cvt(const float* __restrict__ src,
                                              u16* __restrict__ dst, int K, int N) {
  __shared__ u16 tile[64][72];   // +8 pad
  int k0 = blockIdx.x * 64, n0 = blockIdx.y * 64;
  #pragma unroll
  for (int t = 0; t < 16; ++t) {
    int idx = threadIdx.x + t * 256;
    int r = idx >> 6, c = idx & 63;
    tile[r][c] = f2b(src[(size_t)(k0 + r) * N + n0 + c]);
  }
  __syncthreads();
  #pragma unroll
  for (int t = 0; t < 16; ++t) {
    int idx = threadIdx.x + t * 256;
    int r = idx >> 6, c = idx & 63;       // r = local n, c = local k
    dst[(size_t)(n0 + r) * K + k0 + c] = tile[c][r];
  }
}

// ---------------- GEMM: C[M][N] = A[M][K] * Bt[N][K]^T + bias ----------------
// EPI 0: scatter to q (scaled) / k / v^T.  EPI 1: fp32 out [M][N].
template <int EPI>
__global__ __launch_bounds__(256) void gemm_bt(const u16* __restrict__ A,
                                               const u16* __restrict__ Bt,
                                               const float* __restrict__ bias,
                                               int K, int N,
                                               u16* __restrict__ out_qkv,
                                               float* __restrict__ out_f) {
  __shared__ __align__(16) u16 As[128 * 32];
  __shared__ __align__(16) u16 Bs[128 * 32];
  const int tid = threadIdx.x;
  const int wave = tid >> 6, lane = tid & 63;
  const int m0 = blockIdx.x * 128, n0 = blockIdx.y * 128;
  const int wr = (wave >> 1) * 64, wc = (wave & 1) * 64;
  const int lr = lane & 15, lk = lane >> 4;

  f32x4 acc[4][4] = {};

  for (int kt = 0; kt < K; kt += 32) {
    #pragma unroll
    for (int i = 0; i < 2; ++i) {
      int ch = (wave * 2 + i) * 64 + lane;     // 16B chunk id, 0..511
      int row = ch >> 2, c4 = ch & 3;
      const u16* ga = A + (size_t)(m0 + row) * K + kt + c4 * 8;
      __builtin_amdgcn_global_load_lds((gptr_t)ga, (sptr_t)(As + (wave * 2 + i) * 512), 16, 0, 0);
      const u16* gb = Bt + (size_t)(n0 + row) * K + kt + c4 * 8;
      __builtin_amdgcn_global_load_lds((gptr_t)gb, (sptr_t)(Bs + (wave * 2 + i) * 512), 16, 0, 0);
    }
    __syncthreads();
    bf16x8 af[4], bfr[4];
    #pragma unroll
    for (int mi = 0; mi < 4; ++mi)
      af[mi] = *(const bf16x8*)(As + (wr + mi * 16 + lr) * 32 + lk * 8);
    #pragma unroll
    for (int ni = 0; ni < 4; ++ni)
      bfr[ni] = *(const bf16x8*)(Bs + (wc + ni * 16 + lr) * 32 + lk * 8);
    #pragma unroll
    for (int mi = 0; mi < 4; ++mi)
      #pragma unroll
      for (int ni = 0; ni < 4; ++ni)
        acc[mi][ni] = __builtin_amdgcn_mfma_f32_16x16x32_bf16(af[mi], bfr[ni], acc[mi][ni], 0, 0, 0);
    __syncthreads();
  }

  #pragma unroll
  for (int mi = 0; mi < 4; ++mi) {
    #pragma unroll
    for (int ni = 0; ni < 4; ++ni) {
      #pragma unroll
      for (int j = 0; j < 4; ++j) {
        int m = m0 + wr + mi * 16 + lk * 4 + j;    // C/D: row=(lane>>4)*4+reg
        int n = n0 + wc + ni * 16 + lr;            //      col=lane&15
        float val = acc[mi][ni][j] + bias[n];
        if (EPI == 0) {
          int sel = n >> 10, rem = n & 1023;
          int h = rem >> 6, d = rem & 63;
          int b = m >> 11, t = m & 2047;
          size_t base = (size_t)sel * QKVSZ;
          if (sel == 0)
            out_qkv[base + (((size_t)(b * H_ + h) * T_ + t) * HD_ + d)] = f2b(val * QSCALE);
          else if (sel == 1)
            out_qkv[base + (((size_t)(b * H_ + h) * T_ + t) * HD_ + d)] = f2b(val);
          else  // v stored transposed: [b,h,d,t]
            out_qkv[base + (((size_t)(b * H_ + h) * HD_ + d) * T_ + t)] = f2b(val);
        } else {
          out_f[(size_t)m * C_ + n] = val;
        }
      }
    }
  }
}

// ---------------- causal flash attention ----------------
// 128 threads = 2 waves; q-tile 128 (wave w owns q in [BQ+64w, BQ+64w+64)).
// 32x32x16 MFMAs. S^T = mfma(K, Q): lane (hi=lane>>5, lq=lane&31) holds, for
// q = BQ+64w+32qs+lq, k_local = 32kh + 4hi + (reg&3) + 8*(reg>>2).
// Softmax per-lane + 1 shfl_xor(32). P stays in registers: cvt_pk pairs +
// permlane32_swap assemble the PV B-fragment (no LDS round trip).
// O^T = mfma(Vt, P). K/V staged via global_load_lds, dbuf, granule-XOR swizzle.
__global__ __launch_bounds__(128, 2) void attn_k(const u16* __restrict__ q,
                                                 const u16* __restrict__ k,
                                                 const u16* __restrict__ vt,
                                                 u16* __restrict__ y) {
  __shared__ __align__(16) u16 Ks[2][64 * 64];
  __shared__ __align__(16) u16 Vs[2][64 * 64];
  const int tid = threadIdx.x;
  const int wave = tid >> 6, lane = tid & 63;
  const int hi = lane >> 5, lq = lane & 31;
  const int qtb = gridDim.y - 1 - blockIdx.y;    // heavy tiles dispatched first
  const int bh = blockIdx.x;                     // fastest dim -> spreads XCDs
  const size_t koff = (size_t)bh * T_ * HD_;     // q,k: [bh][t][d]
  const size_t voff = (size_t)bh * HD_ * T_;     // vt:  [bh][d][t]
  const int BQ = qtb * 128;
  const int qrow = BQ + 64 * wave + lq;          // +32*qs

  // Q B-frags (q pre-scaled by 0.125*log2e): qf[qs][c] = Q[qrow+32qs][16c+8hi..+7]
  bf16x8 qf[2][4];
  #pragma unroll
  for (int qs = 0; qs < 2; ++qs)
    #pragma unroll
    for (int c = 0; c < 4; ++c)
      qf[qs][c] = *(const bf16x8*)(q + koff + (size_t)(qrow + 32 * qs) * HD_ + 16 * c + 8 * hi);

  f32x16 o[2][2] = {};                           // [qs][dh]
  float mrun[2] = {-1e30f, -1e30f};
  float lsum[2] = {0.f, 0.f};

  auto stage = [&](int buf, int kt) {
    const u16* kb = k + koff + (size_t)kt * 64 * HD_;
    const u16* vb = vt + voff + (size_t)kt * 64;
    #pragma unroll
    for (int j = 0; j < 4; ++j) {
      int cb = j * 128 + wave * 64;              // wave-uniform chunk base
      int ch = cb + lane;
      int row = ch >> 3, gg = ch & 7;
      int src = gg ^ (row & 7);                  // pre-swizzled global source
      __builtin_amdgcn_global_load_lds((gptr_t)(kb + row * HD_ + src * 8),
                                       (sptr_t)(&Ks[buf][cb * 8]), 16, 0, 0);
      __builtin_amdgcn_global_load_lds((gptr_t)(vb + (size_t)row * T_ + src * 8),
                                       (sptr_t)(&Vs[buf][cb * 8]), 16, 0, 0);
    }
  };

  const int nt = 2 * qtb + 2;
  stage(0, 0);
  __syncthreads();

  for (int kt = 0; kt < nt; ++kt) {
    const int cur = kt & 1;
    if (kt + 1 < nt) stage(cur ^ 1, kt + 1);
    const bool active = (kt <= 2 * qtb + wave);
    if (active) {
      const u16* Kb = &Ks[cur][0];
      const u16* Vb = &Vs[cur][0];

      // ---- S^T = K Q^T : s[kh][qs], K A-frags read once, reused for both qs
      f32x16 s[2][2] = {};
      #pragma unroll
      for (int c = 0; c < 4; ++c) {
        #pragma unroll
        for (int kh = 0; kh < 2; ++kh) {
          int row = 32 * kh + lq;
          bf16x8 kf = *(const bf16x8*)(Kb + row * 64 + (((2 * c + hi) ^ (row & 7)) << 3));
          s[kh][0] = __builtin_amdgcn_mfma_f32_32x32x16_bf16(kf, qf[0][c], s[kh][0], 0, 0, 0);
          s[kh][1] = __builtin_amdgcn_mfma_f32_32x32x16_bf16(kf, qf[1][c], s[kh][1], 0, 0, 0);
        }
      }

      const bool diag = (kt == 2 * qtb + wave);  // one straddle tile per wave
      if (diag) {
        #pragma unroll
        for (int qs = 0; qs < 2; ++qs) {
          int qg = qrow + 32 * qs;
          #pragma unroll
          for (int rr = 0; rr < 16; ++rr) {
            int kg = 64 * kt + 4 * hi + (rr & 3) + 8 * (rr >> 2);
            if (kg > qg)      s[0][qs][rr] = -1e30f;
            if (kg + 32 > qg) s[1][qs][rr] = -1e30f;
          }
        }
      }

      // ---- online softmax per qs (lane and lane^32 share a q-row) ----
      #pragma unroll
      for (int qs = 0; qs < 2; ++qs) {
        float tm = -1e30f;
        #pragma unroll
        for (int rr = 0; rr < 16; ++rr) {
          tm = fmaxf(tm, s[0][qs][rr]);
          tm = fmaxf(tm, s[1][qs][rr]);
        }
        tm = fmaxf(tm, __shfl_xor(tm, 32));
        if (__any(tm > mrun[qs] + 8.f)) {        // defer-max (T13)
          float mn = fmaxf(mrun[qs], tm);
          float al = exp2f(mrun[qs] - mn);
          lsum[qs] *= al;
          o[qs][0] *= al;
          o[qs][1] *= al;
          mrun[qs] = mn;
        }
        float rs = 0.f;
        #pragma unroll
        for (int kh = 0; kh < 2; ++kh)
          #pragma unroll
          for (int rr = 0; rr < 16; ++rr) {
            float p = exp2f(s[kh][qs][rr] - mrun[qs]);
            s[kh][qs][rr] = p;
            rs += p;
          }
        rs += __shfl_xor(rs, 32);
        lsum[qs] += rs;
      }

      // ---- PV: O^T[d][q] += Vt P, P assembled in-register via pk+permlane ----
      #pragma unroll
      for (int kh = 0; kh < 2; ++kh) {
        bf16x8 pf[2][2];
        #pragma unroll
        for (int qs = 0; qs < 2; ++qs)
          #pragma unroll
          for (int ct = 0; ct < 2; ++ct) {
            u32 A0 = cvtpk(s[kh][qs][8 * ct + 0], s[kh][qs][8 * ct + 1]);
            u32 A1 = cvtpk(s[kh][qs][8 * ct + 2], s[kh][qs][8 * ct + 3]);
            u32 B0 = cvtpk(s[kh][qs][8 * ct + 4], s[kh][qs][8 * ct + 5]);
            u32 B1 = cvtpk(s[kh][qs][8 * ct + 6], s[kh][qs][8 * ct + 7]);
            i32x2 r0 = __builtin_amdgcn_permlane32_swap((int)A0, (int)B0, false, false);
            i32x2 r1 = __builtin_amdgcn_permlane32_swap((int)A1, (int)B1, false, false);
            u32x4 w = {(u32)r0[0], (u32)r1[0], (u32)r0[1], (u32)r1[1]};
            pf[qs][ct] = __builtin_bit_cast(bf16x8, w);
          }
        #pragma unroll
        for (int ct = 0; ct < 2; ++ct)
          #pragma unroll
          for (int dh = 0; dh < 2; ++dh) {
            int row = 32 * dh + lq;
            bf16x8 vf = *(const bf16x8*)(Vb + row * 64 + (((4 * kh + 2 * ct + hi) ^ (row & 7)) << 3));
            o[0][dh] = __builtin_amdgcn_mfma_f32_32x32x16_bf16(vf, pf[0][ct], o[0][dh], 0, 0, 0);
            o[1][dh] = __builtin_amdgcn_mfma_f32_32x32x16_bf16(vf, pf[1][ct], o[1][dh], 0, 0, 0);
          }
      }
    }
    __syncthreads();
  }

  // ---- epilogue: y[b,t,h*64+d] = O^T[d][q] / l ----
  const int b = bh >> 4, h = bh & 15;
  #pragma unroll
  for (int qs = 0; qs < 2; ++qs) {
    float li = 1.0f / lsum[qs];
    int t = qrow + 32 * qs;
    u16* yrow = y + (size_t)(b * T_ + t) * C_ + h * 64;
    #pragma unroll
    for (int dh = 0; dh < 2; ++dh)
      #pragma unroll
      for (int u = 0; u < 4; ++u) {
        ushort4 st;
        st.x = f2b(o[qs][dh][4 * u + 0] * li);
        st.y = f2b(o[qs][dh][4 * u + 1] * li);
        st.z = f2b(o[qs][dh][4 * u + 2] * li);
        st.w = f2b(o[qs][dh][4 * u + 3] * li);
        *(ushort4*)(yrow + 32 * dh + 8 * u + 4 * hi) = st;
      }
  }
}

extern "C" void kernel_launch(void* const* d_in, const int* in_sizes, int n_in,
                              void* d_out, int out_size, void* d_ws, size_t ws_size,
                              hipStream_t stream) {
  const float* x      = (const float*)d_in[0];
  const float* W_attn = (const float*)d_in[1];
  const float* b_attn = (const float*)d_in[2];
  const float* W_proj = (const float*)d_in[3];
  const float* b_proj = (const float*)d_in[4];
  float* out = (float*)d_out;

  u16* ws = (u16*)d_ws;
  u16* xb  = ws;
  u16* Wat = xb + (size_t)M_ * C_;
  u16* Wpt = Wat + (size_t)N3_ * C_;
  u16* qkv = Wpt + (size_t)C_ * C_;
  u16* y   = qkv + (size_t)3 * QKVSZ;

  cvt_kernel<<<2048, 256, 0, stream>>>(x, xb, M_ * C_ / 4);
  tr_cvt<<<dim3(C_ / 64, N3_ / 64), 256, 0, stream>>>(W_attn, Wat, C_, N3_);
  tr_cvt<<<dim3(C_ / 64, C_ / 64), 256, 0, stream>>>(W_proj, Wpt, C_, C_);
  gemm_bt<0><<<dim3(M_ / 128, N3_ / 128), 256, 0, stream>>>(xb, Wat, b_attn, C_, N3_, qkv, nullptr);
  attn_k<<<dim3(B_ * H_, T_ / 128), 128, 0, stream>>>(qkv, qkv + QKVSZ, qkv + 2 * QKVSZ, y);
  gemm_bt<1><<<dim3(M_ / 128, C_ / 128), 256, 0, stream>>>(y, Wpt, b_proj, C_, C_, nullptr, out);
}

// Round 4
// 209.455 us; speedup vs baseline: 1.9054x; 1.0920x over previous
//
#include <hip/hip_runtime.h>
#include <hip/hip_bf16.h>

#define B_ 4
#define T_ 2048
#define C_ 1024
#define H_ 16
#define HD_ 64
#define M_ (B_*T_)        // 8192 rows
#define N3_ (3*C_)        // 3072
#define QKVSZ (B_*H_*T_*HD_)  // 8388608 elems per tensor
#define QSCALE 0.1803368801f  // 0.125 * log2(e)

typedef unsigned short u16;
typedef unsigned int u32;
typedef __attribute__((ext_vector_type(8))) __bf16 bf16x8;
typedef __attribute__((ext_vector_type(4))) float f32x4;
typedef __attribute__((ext_vector_type(16))) float f32x16;
typedef __attribute__((ext_vector_type(2))) int i32x2;
typedef __attribute__((ext_vector_type(4))) u32 u32x4;
typedef const __attribute__((address_space(1))) void* gptr_t;
typedef __attribute__((address_space(3))) void* sptr_t;

__device__ __forceinline__ u16 f2b(float f) {
  __hip_bfloat16 h = __float2bfloat16(f);
  return __builtin_bit_cast(u16, h);
}

// v_cvt_pk_bf16_f32: lo -> bits[15:0], hi -> bits[31:16]
__device__ __forceinline__ u32 cvtpk(float lo, float hi) {
  u32 r;
  asm volatile("v_cvt_pk_bf16_f32 %0, %1, %2" : "=v"(r) : "v"(lo), "v"(hi));
  return r;
}

// ---------------- fp32 -> bf16 convert (vectorized) ----------------
__global__ __launch_bounds__(256) void cvt_kernel(const float* __restrict__ src,
                                                  u16* __restrict__ dst, int n4) {
  int i = blockIdx.x * blockDim.x + threadIdx.x;
  int stride = gridDim.x * blockDim.x;
  for (; i < n4; i += stride) {
    float4 f = ((const float4*)src)[i];
    ushort4 o;
    o.x = f2b(f.x); o.y = f2b(f.y); o.z = f2b(f.z); o.w = f2b(f.w);
    ((ushort4*)dst)[i] = o;
  }
}

// ---------------- transpose + convert: src[K][N] fp32 -> dst[N][K] bf16 ----------------
__global__ __launch_bounds__(256) void tr_cvt(const float* __restrict__ src,
                                              u16* __restrict__ dst, int K, int N) {
  __shared__ u16 tile[64][72];   // +8 pad
  int k0 = blockIdx.x * 64, n0 = blockIdx.y * 64;
  #pragma unroll
  for (int t = 0; t < 16; ++t) {
    int idx = threadIdx.x + t * 256;
    int r = idx >> 6, c = idx & 63;
    tile[r][c] = f2b(src[(size_t)(k0 + r) * N + n0 + c]);
  }
  __syncthreads();
  #pragma unroll
  for (int t = 0; t < 16; ++t) {
    int idx = threadIdx.x + t * 256;
    int r = idx >> 6, c = idx & 63;       // r = local n, c = local k
    dst[(size_t)(n0 + r) * K + k0 + c] = tile[c][r];
  }
}

// ---------------- GEMM: C[M][N] = A[M][K] * Bt[N][K]^T + bias ----------------
// EPI 0: scatter to q (scaled) / k / v^T.  EPI 1: fp32 out [M][N].
template <int EPI>
__global__ __launch_bounds__(256) void gemm_bt(const u16* __restrict__ A,
                                               const u16* __restrict__ Bt,
                                               const float* __restrict__ bias,
                                               int K, int N,
                                               u16* __restrict__ out_qkv,
                                               float* __restrict__ out_f) {
  __shared__ __align__(16) u16 As[128 * 32];
  __shared__ __align__(16) u16 Bs[128 * 32];
  const int tid = threadIdx.x;
  const int wave = tid >> 6, lane = tid & 63;
  const int m0 = blockIdx.x * 128, n0 = blockIdx.y * 128;
  const int wr = (wave >> 1) * 64, wc = (wave & 1) * 64;
  const int lr = lane & 15, lk = lane >> 4;

  f32x4 acc[4][4] = {};

  for (int kt = 0; kt < K; kt += 32) {
    #pragma unroll
    for (int i = 0; i < 2; ++i) {
      int ch = (wave * 2 + i) * 64 + lane;     // 16B chunk id, 0..511
      int row = ch >> 2, c4 = ch & 3;
      const u16* ga = A + (size_t)(m0 + row) * K + kt + c4 * 8;
      __builtin_amdgcn_global_load_lds((gptr_t)ga, (sptr_t)(As + (wave * 2 + i) * 512), 16, 0, 0);
      const u16* gb = Bt + (size_t)(n0 + row) * K + kt + c4 * 8;
      __builtin_amdgcn_global_load_lds((gptr_t)gb, (sptr_t)(Bs + (wave * 2 + i) * 512), 16, 0, 0);
    }
    __syncthreads();
    bf16x8 af[4], bfr[4];
    #pragma unroll
    for (int mi = 0; mi < 4; ++mi)
      af[mi] = *(const bf16x8*)(As + (wr + mi * 16 + lr) * 32 + lk * 8);
    #pragma unroll
    for (int ni = 0; ni < 4; ++ni)
      bfr[ni] = *(const bf16x8*)(Bs + (wc + ni * 16 + lr) * 32 + lk * 8);
    #pragma unroll
    for (int mi = 0; mi < 4; ++mi)
      #pragma unroll
      for (int ni = 0; ni < 4; ++ni)
        acc[mi][ni] = __builtin_amdgcn_mfma_f32_16x16x32_bf16(af[mi], bfr[ni], acc[mi][ni], 0, 0, 0);
    __syncthreads();
  }

  #pragma unroll
  for (int mi = 0; mi < 4; ++mi) {
    #pragma unroll
    for (int ni = 0; ni < 4; ++ni) {
      #pragma unroll
      for (int j = 0; j < 4; ++j) {
        int m = m0 + wr + mi * 16 + lk * 4 + j;    // C/D: row=(lane>>4)*4+reg
        int n = n0 + wc + ni * 16 + lr;            //      col=lane&15
        float val = acc[mi][ni][j] + bias[n];
        if (EPI == 0) {
          int sel = n >> 10, rem = n & 1023;
          int h = rem >> 6, d = rem & 63;
          int b = m >> 11, t = m & 2047;
          size_t base = (size_t)sel * QKVSZ;
          if (sel == 0)
            out_qkv[base + (((size_t)(b * H_ + h) * T_ + t) * HD_ + d)] = f2b(val * QSCALE);
          else if (sel == 1)
            out_qkv[base + (((size_t)(b * H_ + h) * T_ + t) * HD_ + d)] = f2b(val);
          else  // v stored transposed: [b,h,d,t]
            out_qkv[base + (((size_t)(b * H_ + h) * HD_ + d) * T_ + t)] = f2b(val);
        } else {
          out_f[(size_t)m * C_ + n] = val;
        }
      }
    }
  }
}

// ---------------- causal flash attention ----------------
// 128 threads = 2 waves; q-tile 64 (wave w owns q-rows [BQ+32w, BQ+32w+32)).
// grid (bh=64, 32 q-tiles) = 2048 blocks, heavy-first -> HW dispatcher refills
// as light blocks finish (work balance) and ~5 blocks/CU resident (LDS cap).
// 32x32x16 MFMAs, swapped S^T = mfma(K,Q). Softmax per-lane + 1 shfl_xor(32).
// P stays in registers via cvt_pk + permlane32_swap. O^T = mfma(Vt, P).
// Wave 0's diag tile has its upper kh-half fully masked -> skipped outright.
__global__ __launch_bounds__(128, 2) void attn_k(const u16* __restrict__ q,
                                                 const u16* __restrict__ k,
                                                 const u16* __restrict__ vt,
                                                 u16* __restrict__ y) {
  __shared__ __align__(16) u16 Ks[2][64 * 64];
  __shared__ __align__(16) u16 Vs[2][64 * 64];
  const int tid = threadIdx.x;
  const int wave = tid >> 6, lane = tid & 63;
  const int hi = lane >> 5, lq = lane & 31;
  const int qtb = gridDim.y - 1 - blockIdx.y;    // 31..0, heavy first
  const int bh = blockIdx.x;                     // fastest dim -> XCD spread
  const size_t koff = (size_t)bh * T_ * HD_;     // q,k: [bh][t][d]
  const size_t voff = (size_t)bh * HD_ * T_;     // vt:  [bh][d][t]
  const int qrow = qtb * 64 + 32 * wave + lq;    // this lane's q row (global)

  // Q B-frags (pre-scaled by 0.125*log2e): qf[c] = Q[qrow][16c+8hi .. +8]
  bf16x8 qf[4];
  #pragma unroll
  for (int c = 0; c < 4; ++c)
    qf[c] = *(const bf16x8*)(q + koff + (size_t)qrow * HD_ + 16 * c + 8 * hi);

  f32x16 o[2] = {};                              // [dh]: O^T rows 32dh..
  float mrun = -1e30f, lsum = 0.f;

  auto stage = [&](int buf, int kt) {
    const u16* kb = k + koff + (size_t)kt * 64 * HD_;
    const u16* vb = vt + voff + (size_t)kt * 64;
    #pragma unroll
    for (int j = 0; j < 4; ++j) {
      int cb = j * 128 + wave * 64;              // wave-uniform chunk base
      int ch = cb + lane;
      int row = ch >> 3, gg = ch & 7;
      int src = gg ^ (row & 7);                  // pre-swizzled global source
      __builtin_amdgcn_global_load_lds((gptr_t)(kb + row * HD_ + src * 8),
                                       (sptr_t)(&Ks[buf][cb * 8]), 16, 0, 0);
      __builtin_amdgcn_global_load_lds((gptr_t)(vb + (size_t)row * T_ + src * 8),
                                       (sptr_t)(&Vs[buf][cb * 8]), 16, 0, 0);
    }
  };

  const int nt = qtb + 1;
  stage(0, 0);
  __syncthreads();

  for (int kt = 0; kt < nt; ++kt) {
    const int cur = kt & 1;
    if (kt + 1 < nt) stage(cur ^ 1, kt + 1);
    const bool dia = (kt == qtb);
    const bool skip1 = dia && (wave == 0);       // kh=1 fully masked (wave-uniform)
    const u16* Kb = &Ks[cur][0];
    const u16* Vb = &Vs[cur][0];

    // ---- S^T = K Q^T ----
    f32x16 s[2] = {};
    #pragma unroll
    for (int c = 0; c < 4; ++c) {
      #pragma unroll
      for (int kh = 0; kh < 2; ++kh) {
        if (kh == 1 && skip1) continue;
        int row = 32 * kh + lq;
        bf16x8 kf = *(const bf16x8*)(Kb + row * 64 + (((2 * c + hi) ^ (row & 7)) << 3));
        s[kh] = __builtin_amdgcn_mfma_f32_32x32x16_bf16(kf, qf[c], s[kh], 0, 0, 0);
      }
    }

    if (dia) {
      // wave 0: kh0 diagonal-masked; wave 1: kh0 fully visible, kh1 diagonal-masked
      #pragma unroll
      for (int rr = 0; rr < 16; ++rr) {
        int kg = 64 * kt + 4 * hi + (rr & 3) + 8 * (rr >> 2);
        if (wave == 0) { if (kg > qrow) s[0][rr] = -1e30f; }
        else           { if (kg + 32 > qrow) s[1][rr] = -1e30f; }
      }
    }

    // ---- online softmax (lane and lane^32 share a q-row) ----
    float tm = -1e30f;
    #pragma unroll
    for (int kh = 0; kh < 2; ++kh) {
      if (kh == 1 && skip1) continue;
      #pragma unroll
      for (int rr = 0; rr < 16; ++rr) tm = fmaxf(tm, s[kh][rr]);
    }
    tm = fmaxf(tm, __shfl_xor(tm, 32));
    if (__any(tm > mrun + 8.f)) {                // defer-max (T13)
      float mn = fmaxf(mrun, tm);
      float al = exp2f(mrun - mn);
      lsum *= al;
      o[0] *= al;
      o[1] *= al;
      mrun = mn;
    }
    float rs = 0.f;
    #pragma unroll
    for (int kh = 0; kh < 2; ++kh) {
      if (kh == 1 && skip1) continue;
      #pragma unroll
      for (int rr = 0; rr < 16; ++rr) {
        float p = exp2f(s[kh][rr] - mrun);
        s[kh][rr] = p;
        rs += p;
      }
    }
    rs += __shfl_xor(rs, 32);
    lsum += rs;

    // ---- PV: O^T[d][q] += Vt P (P assembled in-register) ----
    #pragma unroll
    for (int kh = 0; kh < 2; ++kh) {
      if (kh == 1 && skip1) continue;
      bf16x8 pf[2];
      #pragma unroll
      for (int ct = 0; ct < 2; ++ct) {
        u32 A0 = cvtpk(s[kh][8 * ct + 0], s[kh][8 * ct + 1]);
        u32 A1 = cvtpk(s[kh][8 * ct + 2], s[kh][8 * ct + 3]);
        u32 B0 = cvtpk(s[kh][8 * ct + 4], s[kh][8 * ct + 5]);
        u32 B1 = cvtpk(s[kh][8 * ct + 6], s[kh][8 * ct + 7]);
        i32x2 r0 = __builtin_amdgcn_permlane32_swap((int)A0, (int)B0, false, false);
        i32x2 r1 = __builtin_amdgcn_permlane32_swap((int)A1, (int)B1, false, false);
        u32x4 w = {(u32)r0[0], (u32)r1[0], (u32)r0[1], (u32)r1[1]};
        pf[ct] = __builtin_bit_cast(bf16x8, w);
      }
      #pragma unroll
      for (int ct = 0; ct < 2; ++ct)
        #pragma unroll
        for (int dh = 0; dh < 2; ++dh) {
          int row = 32 * dh + lq;
          bf16x8 vf = *(const bf16x8*)(Vb + row * 64 + (((4 * kh + 2 * ct + hi) ^ (row & 7)) << 3));
          o[dh] = __builtin_amdgcn_mfma_f32_32x32x16_bf16(vf, pf[ct], o[dh], 0, 0, 0);
        }
    }
    __syncthreads();
  }

  // ---- epilogue: y[b,t,h*64+d] = O^T[d][q] / l ----
  const int b = bh >> 4, h = bh & 15;
  float li = 1.0f / lsum;
  u16* yrow = y + (size_t)(b * T_ + qrow) * C_ + h * 64;
  #pragma unroll
  for (int dh = 0; dh < 2; ++dh)
    #pragma unroll
    for (int u = 0; u < 4; ++u) {
      ushort4 st;
      st.x = f2b(o[dh][4 * u + 0] * li);
      st.y = f2b(o[dh][4 * u + 1] * li);
      st.z = f2b(o[dh][4 * u + 2] * li);
      st.w = f2b(o[dh][4 * u + 3] * li);
      *(ushort4*)(yrow + 32 * dh + 8 * u + 4 * hi) = st;
    }
}

extern "C" void kernel_launch(void* const* d_in, const int* in_sizes, int n_in,
                              void* d_out, int out_size, void* d_ws, size_t ws_size,
                              hipStream_t stream) {
  const float* x      = (const float*)d_in[0];
  const float* W_attn = (const float*)d_in[1];
  const float* b_attn = (const float*)d_in[2];
  const float* W_proj = (const float*)d_in[3];
  const float* b_proj = (const float*)d_in[4];
  float* out = (float*)d_out;

  u16* ws = (u16*)d_ws;
  u16* xb  = ws;
  u16* Wat = xb + (size_t)M_ * C_;
  u16* Wpt = Wat + (size_t)N3_ * C_;
  u16* qkv = Wpt + (size_t)C_ * C_;
  u16* y   = qkv + (size_t)3 * QKVSZ;

  cvt_kernel<<<2048, 256, 0, stream>>>(x, xb, M_ * C_ / 4);
  tr_cvt<<<dim3(C_ / 64, N3_ / 64), 256, 0, stream>>>(W_attn, Wat, C_, N3_);
  tr_cvt<<<dim3(C_ / 64, C_ / 64), 256, 0, stream>>>(W_proj, Wpt, C_, C_);
  gemm_bt<0><<<dim3(M_ / 128, N3_ / 128), 256, 0, stream>>>(xb, Wat, b_attn, C_, N3_, qkv, nullptr);
  attn_k<<<dim3(B_ * H_, T_ / 64), 128, 0, stream>>>(qkv, qkv + QKVSZ, qkv + 2 * QKVSZ, y);
  gemm_bt<1><<<dim3(M_ / 128, C_ / 128), 256, 0, stream>>>(y, Wpt, b_proj, C_, C_, nullptr, out);
}